// Round 1
// baseline (1425.007 us; speedup 1.0000x reference)
//
#include <hip/hip_runtime.h>

typedef unsigned short u16;
typedef unsigned int   u32;
typedef __bf16 bf16x8 __attribute__((ext_vector_type(8)));
typedef float  f32x4  __attribute__((ext_vector_type(4)));

__device__ __forceinline__ float bf2f(u16 u){
  union { u32 i; float f; } v; v.i = ((u32)u) << 16; return v.f;
}
__device__ __forceinline__ u16 f2bf(float f){
  union { float f; u32 i; } v; v.f = f;
  u32 r = v.i + 0x7fffu + ((v.i >> 16) & 1u);
  return (u16)(r >> 16);
}
__device__ __forceinline__ void bfpair(u32 u, float& lo, float& hi){
  union { u32 i; float f; } a, b;
  a.i = u << 16; b.i = u & 0xffff0000u;
  lo = a.f; hi = b.f;
}
__device__ __forceinline__ float lrelu(float x){ return fmaxf(x, 0.f) + 0.2f * fminf(x, 0.f); }
__device__ __forceinline__ float cexp(float x){ return __expf(fminf(x, 60.f)); }  // insurance clamp
__device__ __forceinline__ float wsum(float p){
  #pragma unroll
  for (int o = 32; o > 0; o >>= 1) p += __shfl_xor(p, o, 64);
  return p;
}

#define NPAR 21

struct PTbl { const void* src[NPAR]; float* dst[NPAR]; int n[NPAR]; };

// ---------------- dtype probe: flag=1 if x is float32, 0 if bf16 ------------
// f32 data: low 16 bits of a word are uniform mantissa junk -> bf16-exponent
// field >= 0xFD with p~1.2%/word. True bf16 N(0,1) data never has exp>=0xFD.
__global__ __launch_bounds__(256) void k_probe(const u32* __restrict__ xw, int* __restrict__ flag){
  __shared__ int sbad;
  if (threadIdx.x == 0) sbad = 0;
  __syncthreads();
  int bad = 0;
  for (int i = threadIdx.x; i < 16384; i += 256){
    u32 w = xw[i];
    int e0 = (w >> 7) & 0xff;        // exponent of low-half-as-bf16
    if (e0 >= 0xFD) bad++;
  }
  if (bad) atomicAdd(&sbad, bad);
  __syncthreads();
  if (threadIdx.x == 0) flag[0] = (sbad > 8) ? 1 : 0;
}

// ---------------- canonicalize all small params to f32 ----------------------
__global__ __launch_bounds__(256) void k_cvt(PTbl tb, const int* __restrict__ flag){
  const int p = blockIdx.y;
  const int n = tb.n[p];
  const int isf32 = flag[0];
  float* d = tb.dst[p];
  for (int i = blockIdx.x * 256 + threadIdx.x; i < n; i += gridDim.x * 256){
    d[i] = isf32 ? ((const float*)tb.src[p])[i] : bf2f(((const u16*)tb.src[p])[i]);
  }
}

// ---------------- Phase A: x[N,4,15000] -> h bf16 [N,1024] (K-padded) -------
__global__ __launch_bounds__(256) void k_front(const void* __restrict__ xraw,
    const float* __restrict__ wcF, const float* __restrict__ cbF,
    const float* __restrict__ w2F, const float* __restrict__ cb2F,
    const int* __restrict__ flag, u16* __restrict__ hbf)
{
  __shared__ float hpre[7560];
  const int b = blockIdx.x, t = threadIdx.x;
  const int nn = b >> 1, half = b & 1;
  const int l0   = half ? 7440 : 0;
  const int ngrp = half ? 945  : 930;   // groups of 8 elements
  const int m0   = half ? 496  : 0;
  const int nm   = half ? 504  : 496;
  const int isf32 = flag[0];
  float wc[4], w2[15];
  #pragma unroll
  for (int c = 0; c < 4; ++c) wc[c] = wcF[c];
  float sw2 = 0.f;
  #pragma unroll
  for (int k = 0; k < 15; ++k){ w2[k] = w2F[k]; sw2 += w2[k]; }
  const float cbias = cbF[0] * sw2 + cb2F[0];

  if (isf32){
    const float4* xf = reinterpret_cast<const float4*>((const float*)xraw + (size_t)nn * 60000 + l0);
    for (int g = t; g < ngrp; g += 256){
      float acc[8] = {0,0,0,0,0,0,0,0};
      #pragma unroll
      for (int c = 0; c < 4; ++c){
        float4 u = xf[c * 3750 + 2 * g];
        float4 v = xf[c * 3750 + 2 * g + 1];
        float wcc = wc[c];
        acc[0] += wcc*u.x; acc[1] += wcc*u.y; acc[2] += wcc*u.z; acc[3] += wcc*u.w;
        acc[4] += wcc*v.x; acc[5] += wcc*v.y; acc[6] += wcc*v.z; acc[7] += wcc*v.w;
      }
      float4* hp = reinterpret_cast<float4*>(&hpre[g * 8]);
      hp[0] = make_float4(acc[0], acc[1], acc[2], acc[3]);
      hp[1] = make_float4(acc[4], acc[5], acc[6], acc[7]);
    }
  } else {
    const uint4* xb = reinterpret_cast<const uint4*>((const u16*)xraw + (size_t)nn * 60000 + l0);
    for (int g = t; g < ngrp; g += 256){
      float acc[8] = {0,0,0,0,0,0,0,0};
      #pragma unroll
      for (int c = 0; c < 4; ++c){
        uint4 v = xb[c * 1875 + g];
        float a, q; float wcc = wc[c];
        bfpair(v.x, a, q); acc[0] += wcc*a; acc[1] += wcc*q;
        bfpair(v.y, a, q); acc[2] += wcc*a; acc[3] += wcc*q;
        bfpair(v.z, a, q); acc[4] += wcc*a; acc[5] += wcc*q;
        bfpair(v.w, a, q); acc[6] += wcc*a; acc[7] += wcc*q;
      }
      float4* hp = reinterpret_cast<float4*>(&hpre[g * 8]);
      hp[0] = make_float4(acc[0], acc[1], acc[2], acc[3]);
      hp[1] = make_float4(acc[4], acc[5], acc[6], acc[7]);
    }
  }
  __syncthreads();
  for (int m = t; m < nm; m += 256){
    float s = cbias;
    const float* hq = &hpre[m * 15];
    #pragma unroll
    for (int k = 0; k < 15; ++k) s += w2[k] * hq[k];
    hbf[(size_t)nn * 1024 + m0 + m] = f2bf(s);
  }
  if (half && t < 24) hbf[(size_t)nn * 1024 + 1000 + t] = 0;  // zero K-pad
}

// ---------------- W1 f32 [1000,512] -> Wt bf16 [512,1024] (T + K-pad) -------
__global__ __launch_bounds__(256) void k_wt(const float* __restrict__ W1F, u16* __restrict__ Wt){
  int idx = blockIdx.x * 256 + threadIdx.x;       // 512*1024 threads
  int n = idx & 511, k = idx >> 9;
  Wt[(size_t)n * 1024 + k] = (k < 1000) ? f2bf(W1F[k * 512 + n]) : (u16)0;
}

// ---------------- init: zero gf1acc/count, xl2 = b2 -------------------------
__global__ __launch_bounds__(256) void k_init(float* __restrict__ gf1acc, int* __restrict__ count,
                                              float* __restrict__ xl2, const float* __restrict__ b2F, int N){
  int i = blockIdx.x * 256 + threadIdx.x;
  if (i < N * 64) gf1acc[i] = 0.f;
  if (i < N){ count[i] = 0; xl2[i] = b2F[0]; }
}

// ---------------- CSR build (counting sort by dst) --------------------------
__global__ __launch_bounds__(256) void k_count(const int* __restrict__ ei, int nE, int N, int* __restrict__ count){
  int e = blockIdx.x * 256 + threadIdx.x;
  if (e >= nE + N) return;
  int d = (e < nE) ? ei[nE + e] : (e - nE);
  d = max(0, min(d, N - 1));
  atomicAdd(&count[d], 1);
}
__global__ __launch_bounds__(256) void k_scan(const int* __restrict__ count, int* __restrict__ rowptr,
                                              int* __restrict__ cursor, int N, int total){
  __shared__ int part[256];
  int t = threadIdx.x;
  int vals[16];
  int base = t * 16, run = 0;
  #pragma unroll
  for (int i = 0; i < 16; ++i){
    int idx = base + i;
    int c = (idx < N) ? count[idx] : 0;
    vals[i] = run; run += c;
  }
  part[t] = run; __syncthreads();
  for (int off = 1; off < 256; off <<= 1){
    int v = (t >= off) ? part[t - off] : 0;
    __syncthreads();
    part[t] += v;
    __syncthreads();
  }
  int excl = (t == 0) ? 0 : part[t - 1];
  #pragma unroll
  for (int i = 0; i < 16; ++i){
    int idx = base + i;
    if (idx < N){ int v = excl + vals[i]; rowptr[idx] = v; cursor[idx] = v; }
  }
  if (t == 255) rowptr[N] = total;
}
__global__ __launch_bounds__(256) void k_scatter(const int* __restrict__ ei, int nE, int N,
                                                 int* __restrict__ cursor, int* __restrict__ srclist){
  int e = blockIdx.x * 256 + threadIdx.x;
  if (e >= nE + N) return;
  int s, d;
  if (e < nE){ s = ei[e]; d = ei[nE + e]; } else { s = e - nE; d = s; }
  s = max(0, min(s, N - 1));
  d = max(0, min(d, N - 1));
  int pos = atomicAdd(&cursor[d], 1);
  srclist[pos] = s;
}

// ---------------- gf = geneflow@fc1+fc1_b (f32) + alphaG[n,h] ---------------
__global__ __launch_bounds__(256) void k_gf(const float* __restrict__ gfinF, const float* __restrict__ fc1wF,
    const float* __restrict__ fc1bF, const float* __restrict__ att1gF,
    float* __restrict__ gfv, float* __restrict__ aG, int N)
{
  int wid  = (blockIdx.x * 256 + threadIdx.x) >> 6;
  int lane = threadIdx.x & 63;
  if (wid >= N) return;
  float gl  = gfinF[(size_t)wid * 64 + lane];
  float acc = fc1bF[lane];
  #pragma unroll 8
  for (int k = 0; k < 64; ++k)
    acc += __shfl(gl, k, 64) * fc1wF[k * 64 + lane];
  gfv[(size_t)wid * 64 + lane] = acc;
  #pragma unroll
  for (int h = 0; h < 8; ++h){
    float p = wsum(acc * att1gF[h * 64 + lane]);
    if (lane == 0) aG[wid * 8 + h] = p;
  }
}

// ---------------- GEMM: xl = h[4000,1024]@Wt^T + b1 -> bf16 [4000,512] ------
__global__ __launch_bounds__(256) void k_gemm(const u16* __restrict__ A, const u16* __restrict__ Bt,
    const float* __restrict__ b1F, u16* __restrict__ C, int M)
{
  __shared__ u16 As[64 * 32];
  __shared__ u16 Bs[64 * 32];
  const int t = threadIdx.x;
  const int bm = blockIdx.x * 64, bn = blockIdx.y * 64;
  const int row = t >> 2, kc = (t & 3) * 8;
  const int wid = t >> 6, lane = t & 63;
  const int wm = (wid >> 1) * 32, wn = (wid & 1) * 32;
  const int fm = lane & 15, fk = (lane >> 4) * 8;
  f32x4 acc[2][2];
  #pragma unroll
  for (int i = 0; i < 2; ++i)
    #pragma unroll
    for (int j = 0; j < 2; ++j) acc[i][j] = (f32x4){0.f, 0.f, 0.f, 0.f};
  const int gm = bm + row;
  const u16* arow = A  + (size_t)gm * 1024 + kc;
  const u16* brow = Bt + (size_t)(bn + row) * 1024 + kc;
  for (int kt = 0; kt < 32; ++kt){
    uint4 av = make_uint4(0, 0, 0, 0);
    if (gm < M) av = *reinterpret_cast<const uint4*>(arow + kt * 32);
    uint4 bv = *reinterpret_cast<const uint4*>(brow + kt * 32);
    __syncthreads();
    *reinterpret_cast<uint4*>(&As[row * 32 + kc]) = av;
    *reinterpret_cast<uint4*>(&Bs[row * 32 + kc]) = bv;
    __syncthreads();
    bf16x8 a0  = *reinterpret_cast<const bf16x8*>(&As[(wm      + fm) * 32 + fk]);
    bf16x8 a1  = *reinterpret_cast<const bf16x8*>(&As[(wm + 16 + fm) * 32 + fk]);
    bf16x8 b0  = *reinterpret_cast<const bf16x8*>(&Bs[(wn      + fm) * 32 + fk]);
    bf16x8 b1f = *reinterpret_cast<const bf16x8*>(&Bs[(wn + 16 + fm) * 32 + fk]);
    acc[0][0] = __builtin_amdgcn_mfma_f32_16x16x32_bf16(a0, b0,  acc[0][0], 0, 0, 0);
    acc[0][1] = __builtin_amdgcn_mfma_f32_16x16x32_bf16(a0, b1f, acc[0][1], 0, 0, 0);
    acc[1][0] = __builtin_amdgcn_mfma_f32_16x16x32_bf16(a1, b0,  acc[1][0], 0, 0, 0);
    acc[1][1] = __builtin_amdgcn_mfma_f32_16x16x32_bf16(a1, b1f, acc[1][1], 0, 0, 0);
  }
  #pragma unroll
  for (int i = 0; i < 2; ++i)
    #pragma unroll
    for (int j = 0; j < 2; ++j)
      #pragma unroll
      for (int r = 0; r < 4; ++r){
        int gr = bm + wm + i * 16 + (lane >> 4) * 4 + r;    // row = quad*4+reg (m89)
        int gc = bn + wn + j * 16 + (lane & 15);            // col = lane&15
        if (gr < M) C[(size_t)gr * 512 + gc] = f2bf(acc[i][j][r] + b1F[gc]);
      }
}

// ---------------- alphaF[n,h] = dot(xl[n,h,:], att1f[h,:]) ------------------
__global__ __launch_bounds__(256) void k_n1(const u16* __restrict__ xl, const float* __restrict__ att1fF,
                                            float* __restrict__ aF, int N){
  int wid  = (blockIdx.x * 256 + threadIdx.x) >> 6;
  int lane = threadIdx.x & 63;
  if (wid >= N * 8) return;
  int n = wid >> 3, h = wid & 7;
  float p = bf2f(xl[(size_t)n * 512 + h * 64 + lane]) * att1fF[h * 64 + lane];
  p = wsum(p);
  if (lane == 0) aF[n * 8 + h] = p;
}

// ---------------- Layer-1 aggregation: wave per (dst,head), lane = channel --
__global__ __launch_bounds__(256) void k_agg1(const int* __restrict__ rowptr, const int* __restrict__ srclist,
    const u16* __restrict__ xl, const float* __restrict__ gfv,
    const float* __restrict__ aF, const float* __restrict__ aG,
    const float* __restrict__ bias1fF, const float* __restrict__ W2F,
    float* __restrict__ gf1acc, float* __restrict__ xl2, int N)
{
  int wid  = (blockIdx.x * 256 + threadIdx.x) >> 6;
  int lane = threadIdx.x & 63;
  if (wid >= N * 8) return;
  int n = wid >> 3, h = wid & 7;
  int e0 = rowptr[n], e1 = rowptr[n + 1];
  float aFd = aF[n * 8 + h], aGd = aG[n * 8 + h];
  float accf = 0.f, accg = 0.f, s1 = 0.f, s2 = 0.f;
  for (int e = e0; e < e1; ++e){
    int s = srclist[e];
    s = max(0, min(s, N - 1));
    float w1 = cexp(lrelu(aFd + aF[s * 8 + h]));   // feature attention (a1)
    float w2 = cexp(lrelu(aGd + aG[s * 8 + h]));   // geneflow attention (a2)
    s1 += w1; s2 += w2;
    accf += w2 * bf2f(xl[(size_t)s * 512 + h * 64 + lane]);  // crossed weighting
    accg += w1 * gfv[(size_t)s * 64 + lane];
  }
  float outf = accf / (s2 + 1e-16f);
  float outg = accg / (s1 + 1e-16f);
  atomicAdd(&gf1acc[n * 64 + lane], outg);           // sum over heads (mean later)
  float v = fmaxf(outf + bias1fF[h * 64 + lane], 0.f);  // relu(h1)
  float p = wsum(v * W2F[h * 64 + lane]);            // fused h1 . W2 partial
  if (lane == 0) atomicAdd(&xl2[n], p);              // xl2 pre-init to b2
}

// ---------------- gf2[n] = relu(mean_h+bias1g) . fc2_w + fc2_b --------------
__global__ __launch_bounds__(256) void k_n2(const float* __restrict__ gf1acc, const float* __restrict__ bias1gF,
    const float* __restrict__ fc2wF, const float* __restrict__ fc2bF, float* __restrict__ gf2, int N){
  int wid  = (blockIdx.x * 256 + threadIdx.x) >> 6;
  int lane = threadIdx.x & 63;
  if (wid >= N) return;
  float v = fmaxf(gf1acc[(size_t)wid * 64 + lane] * 0.125f + bias1gF[lane], 0.f);
  float p = wsum(v * fc2wF[lane]);
  if (lane == 0) gf2[wid] = p + fc2bF[0];
}

// ---------------- Layer-2 aggregation + sigmoid -----------------------------
__global__ __launch_bounds__(256) void k_agg2(const int* __restrict__ rowptr, const int* __restrict__ srclist,
    const float* __restrict__ xl2, const float* __restrict__ gf2,
    const float* __restrict__ att2fF, const float* __restrict__ att2gF,
    const float* __restrict__ bias2fF, const float* __restrict__ bias2gF,
    const int* __restrict__ flag, void* __restrict__ out, int N)
{
  int wid  = (blockIdx.x * 256 + threadIdx.x) >> 6;
  int lane = threadIdx.x & 63;
  if (wid >= N) return;
  int n = wid;
  float xn = xl2[n], gn = gf2[n];
  float af = att2fF[0], ag = att2gF[0];
  int e0 = rowptr[n], e1 = rowptr[n + 1];
  float accf = 0.f, accg = 0.f, s1 = 0.f, s2 = 0.f;
  for (int e = e0 + lane; e < e1; e += 64){
    int s = srclist[e];
    s = max(0, min(s, N - 1));
    float xs = xl2[s], gs = gf2[s];
    float w1 = cexp(lrelu((xn + xs) * af));
    float w2 = cexp(lrelu((gn + gs) * ag));
    s1 += w1; s2 += w2;
    accf += w2 * xs;   // features weighted by a2
    accg += w1 * gs;   // geneflow weighted by a1
  }
  accf = wsum(accf); accg = wsum(accg); s1 = wsum(s1); s2 = wsum(s2);
  if (lane == 0){
    float h2 = accf / (s2 + 1e-16f) + bias2fF[0];
    float g3 = accg / (s1 + 1e-16f) + bias2gF[0];
    float z = h2 + g3;
    float r = 1.f / (1.f + __expf(-z));
    if (flag[0]) ((float*)out)[n] = r;
    else         ((u16*)out)[n]   = f2bf(r);
  }
}

extern "C" void kernel_launch(void* const* d_in, const int* in_sizes, int n_in,
                              void* d_out, int out_size, void* d_ws, size_t ws_size,
                              hipStream_t stream)
{
  const void* x   = d_in[0];
  const int*  ei  = (const int*)d_in[2];

  const int N    = in_sizes[1] / 64;   // 4000
  const int nE   = in_sizes[2] / 2;    // 128000
  const int Etot = nE + N;             // +self loops

  char* w = (char*)d_ws;
  size_t off = 0;
  auto alloc = [&](size_t bytes) -> void* {
    void* p = w + off;
    off += (bytes + 255) & ~(size_t)255;
    return p;
  };
  int*   flag   = (int*)  alloc(256);

  // params canonical f32 block (dict order indices, minus x / edge_index)
  static const int pidx[NPAR] = {1,3,4,5,6,7,8,9,10,11,12,13,14,15,16,17,18,19,20,21,22};
  size_t poff[NPAR], ptot = 0;
  for (int i = 0; i < NPAR; ++i){ poff[i] = ptot; ptot += (size_t)in_sizes[pidx[i]]; }
  float* paramsF = (float*)alloc(ptot * 4);
  PTbl tb;
  for (int i = 0; i < NPAR; ++i){
    tb.src[i] = d_in[pidx[i]];
    tb.dst[i] = paramsF + poff[i];
    tb.n[i]   = in_sizes[pidx[i]];
  }
  const float* gfinF   = paramsF + poff[0];
  const float* cjwF    = paramsF + poff[1];
  const float* cjbF    = paramsF + poff[2];
  const float* cj2wF   = paramsF + poff[3];
  const float* cj2bF   = paramsF + poff[4];
  const float* fc1wF   = paramsF + poff[5];
  const float* fc1bF   = paramsF + poff[6];
  const float* fc2wF   = paramsF + poff[7];
  const float* fc2bF   = paramsF + poff[8];
  const float* W1F     = paramsF + poff[9];
  const float* b1F     = paramsF + poff[10];
  const float* att1fF  = paramsF + poff[11];
  const float* att1gF  = paramsF + poff[12];
  const float* bias1fF = paramsF + poff[13];
  const float* bias1gF = paramsF + poff[14];
  const float* W2F     = paramsF + poff[15];
  const float* b2F     = paramsF + poff[16];
  const float* att2fF  = paramsF + poff[17];
  const float* att2gF  = paramsF + poff[18];
  const float* bias2fF = paramsF + poff[19];
  const float* bias2gF = paramsF + poff[20];

  u16*   hbf    = (u16*)  alloc((size_t)N * 1024 * 2);
  u16*   Wt     = (u16*)  alloc((size_t)512 * 1024 * 2);
  u16*   xl     = (u16*)  alloc((size_t)N * 512 * 2);
  float* gfv    = (float*)alloc((size_t)N * 64 * 4);
  float* aF     = (float*)alloc((size_t)N * 8 * 4);
  float* aG     = (float*)alloc((size_t)N * 8 * 4);
  float* gf1acc = (float*)alloc((size_t)N * 64 * 4);
  float* xl2    = (float*)alloc((size_t)N * 4);
  float* gf2    = (float*)alloc((size_t)N * 4);
  int*   count  = (int*)  alloc((size_t)N * 4);
  int*   rowptr = (int*)  alloc((size_t)(N + 1) * 4);
  int*   cursor = (int*)  alloc((size_t)N * 4);
  int*   srclist= (int*)  alloc((size_t)Etot * 4);

  k_probe  <<<1,                      256, 0, stream>>>((const u32*)x, flag);
  k_cvt    <<<dim3(128, NPAR),        256, 0, stream>>>(tb, flag);
  k_init   <<<(N * 64 + 255) / 256,   256, 0, stream>>>(gf1acc, count, xl2, b2F, N);
  k_count  <<<(Etot + 255) / 256,     256, 0, stream>>>(ei, nE, N, count);
  k_scan   <<<1,                      256, 0, stream>>>(count, rowptr, cursor, N, Etot);
  k_scatter<<<(Etot + 255) / 256,     256, 0, stream>>>(ei, nE, N, cursor, srclist);
  k_front  <<<2 * N,                  256, 0, stream>>>(x, cjwF, cjbF, cj2wF, cj2bF, flag, hbf);
  k_wt     <<<(512 * 1024) / 256,     256, 0, stream>>>(W1F, Wt);
  k_gf     <<<(N + 3) / 4,            256, 0, stream>>>(gfinF, fc1wF, fc1bF, att1gF, gfv, aG, N);
  k_gemm   <<<dim3((N + 63) / 64, 8), 256, 0, stream>>>(hbf, Wt, b1F, xl, N);
  k_n1     <<<(N * 8 + 3) / 4,        256, 0, stream>>>(xl, att1fF, aF, N);
  k_agg1   <<<(N * 8 + 3) / 4,        256, 0, stream>>>(rowptr, srclist, xl, gfv, aF, aG,
                                                        bias1fF, W2F, gf1acc, xl2, N);
  k_n2     <<<(N + 3) / 4,            256, 0, stream>>>(gf1acc, bias1gF, fc2wF, fc2bF, gf2, N);
  k_agg2   <<<(N + 3) / 4,            256, 0, stream>>>(rowptr, srclist, xl2, gf2,
                                                        att2fF, att2gF, bias2fF, bias2gF,
                                                        flag, d_out, N);
}